// Round 1
// baseline (64.867 us; speedup 1.0000x reference)
//
#include <hip/hip_runtime.h>

typedef unsigned short u16;
typedef unsigned int u32;
typedef __bf16 bf16x8 __attribute__((ext_vector_type(8)));
typedef float f32x4 __attribute__((ext_vector_type(4)));

#define B_ 8
#define C_ 64
#define H_ 112
#define W_ 112
#define HW_ 12544
#define F_ 128
#define OH_ 110
#define OW_ 110
#define NPOS 96800
#define KK_ 576

__device__ __forceinline__ u16 f2bf(float f) {
  u32 u = __builtin_bit_cast(u32, f);
  u32 r = (u + 0x7fffu + ((u >> 16) & 1u)) >> 16;
  return (u16)r;
}
__device__ __forceinline__ float bf2f(u16 h) {
  u32 u = ((u32)h) << 16;
  return __builtin_bit_cast(float, u);
}

__device__ __forceinline__ void gl_lds16(const void* g, void* l) {
  __builtin_amdgcn_global_load_lds((const __attribute__((address_space(1))) void*)g,
                                   (__attribute__((address_space(3))) void*)l,
                                   16, 0, 0);
}

// ---------------- prep: NCHW fp32 -> NHWC bf16 hi/lo ----------------
__global__ __launch_bounds__(256) void prep_input(const float* __restrict__ in,
                                                  u16* __restrict__ xH,
                                                  u16* __restrict__ xL) {
  __shared__ float tile[C_][W_ + 1];
  const int b = blockIdx.x / H_;
  const int y = blockIdx.x % H_;
  const int tid = threadIdx.x;
  const float* src = in + ((size_t)b * C_ * H_ + y) * W_;
  for (int idx = tid; idx < C_ * W_; idx += 256) {
    int c = idx / W_;
    int x = idx - c * W_;
    tile[c][x] = src[(size_t)c * HW_ + x];
  }
  __syncthreads();
  const size_t obase = ((size_t)(b * H_ + y)) * W_ * C_;
  for (int idx = tid; idx < W_ * (C_ / 2); idx += 256) {
    int x = idx / (C_ / 2);
    int cp = idx - x * (C_ / 2);
    int c = cp * 2;
    float v0 = tile[c][x], v1 = tile[c + 1][x];
    u16 h0 = f2bf(v0), h1 = f2bf(v1);
    u16 l0 = f2bf(v0 - bf2f(h0)), l1 = f2bf(v1 - bf2f(h1));
    u32 hw = (u32)h0 | ((u32)h1 << 16);
    u32 lw = (u32)l0 | ((u32)l1 << 16);
    *(u32*)(xH + obase + (size_t)x * C_ + c) = hw;
    *(u32*)(xL + obase + (size_t)x * C_ + c) = lw;
  }
}

// ---------------- prep: kernel fp32 -> bf16 hi/lo ----------------
__global__ __launch_bounds__(256) void prep_ker(const float* __restrict__ k,
                                                u16* __restrict__ kH,
                                                u16* __restrict__ kL) {
  int idx = blockIdx.x * 256 + threadIdx.x;
  if (idx < F_ * KK_) {
    float v = k[idx];
    u16 h = f2bf(v);
    kH[idx] = h;
    kL[idx] = f2bf(v - bf2f(h));
  }
}

// ---------------- main: implicit GEMM, 3-term bf16 MFMA ----------------
__global__ __launch_bounds__(256, 2) void conv_mfma(
    const u16* __restrict__ xH, const u16* __restrict__ xL,
    const u16* __restrict__ kH, const u16* __restrict__ kL,
    float* __restrict__ out) {
  __shared__ u16 sAH[F_ * C_];
  __shared__ u16 sAL[F_ * C_];
  __shared__ u16 sBH[128 * C_];
  __shared__ u16 sBL[128 * C_];

  const int tid = threadIdx.x;
  const int wave = tid >> 6;
  const int lane = tid & 63;
  const int n0 = blockIdx.x * 128;

  // staging geometry: per it, wave covers rows (it*4+wave)*8 .. +8, lane>>3 = row-in-group,
  // lane&7 = dst 16B-oct; source oct pre-swizzled so LDS dest stays linear (m173 pattern)
  const int rlo = lane >> 3;
  const int oct_src = (lane & 7) ^ rlo;

  int aOff[4];
  int bOff[4];
#pragma unroll
  for (int it = 0; it < 4; ++it) {
    int row = (it * 4 + wave) * 8 + rlo;
    aOff[it] = row * KK_ + oct_src * 8;
    int n = n0 + row;
    if (n >= NPOS) n = 0;
    int b = n / (OW_ * OH_);
    int r = n - b * (OW_ * OH_);
    int w = r / OH_;
    int h = r - w * OH_;
    bOff[it] = ((b * H_ + h) * W_ + w) * C_ + oct_src * 8;
  }

  const int l15 = lane & 15;
  const int l4 = lane >> 4;
  const int wr = wave >> 1;
  const int wc = wave & 1;

  f32x4 acc[4][4] = {};

  for (int tap = 0; tap < 9; ++tap) {
    const int i = tap / 3;       // x (W) offset
    const int j = tap - i * 3;   // y (H) offset
    const int tapA = tap * C_;
    const int tapB = (j * W_ + i) * C_;

    __syncthreads();  // previous compute done before overwrite
#pragma unroll
    for (int it = 0; it < 4; ++it) {
      const u32 dst = (u32)((it * 4 + wave) * 1024);
      gl_lds16(kH + aOff[it] + tapA, (char*)sAH + dst);
      gl_lds16(kL + aOff[it] + tapA, (char*)sAL + dst);
      gl_lds16(xH + bOff[it] + tapB, (char*)sBH + dst);
      gl_lds16(xL + bOff[it] + tapB, (char*)sBL + dst);
    }
    __syncthreads();  // staged data visible (compiler drains vmcnt before barrier)

#pragma unroll
    for (int ks = 0; ks < 2; ++ks) {
      bf16x8 ah[4], al[4], bh[4], bl[4];
#pragma unroll
      for (int mi = 0; mi < 4; ++mi) {
        int row = wr * 64 + mi * 16 + l15;
        int oo = (ks * 4 + l4) ^ (row & 7);
        int e = row * C_ + oo * 8;
        ah[mi] = *(const bf16x8*)&sAH[e];
        al[mi] = *(const bf16x8*)&sAL[e];
      }
#pragma unroll
      for (int ni = 0; ni < 4; ++ni) {
        int row = wc * 64 + ni * 16 + l15;
        int oo = (ks * 4 + l4) ^ (row & 7);
        int e = row * C_ + oo * 8;
        bh[ni] = *(const bf16x8*)&sBH[e];
        bl[ni] = *(const bf16x8*)&sBL[e];
      }
#pragma unroll
      for (int mi = 0; mi < 4; ++mi)
#pragma unroll
        for (int ni = 0; ni < 4; ++ni) {
          acc[mi][ni] = __builtin_amdgcn_mfma_f32_16x16x32_bf16(ah[mi], bh[ni], acc[mi][ni], 0, 0, 0);
          acc[mi][ni] = __builtin_amdgcn_mfma_f32_16x16x32_bf16(ah[mi], bl[ni], acc[mi][ni], 0, 0, 0);
          acc[mi][ni] = __builtin_amdgcn_mfma_f32_16x16x32_bf16(al[mi], bh[ni], acc[mi][ni], 0, 0, 0);
        }
    }
  }

  // epilogue: D col = lane&15 -> n, row = (lane>>4)*4+q -> f
#pragma unroll
  for (int ni = 0; ni < 4; ++ni) {
    int n = n0 + wc * 64 + ni * 16 + l15;
    if (n >= NPOS) continue;
    int b = n / (OW_ * OH_);
    int r = n - b * (OW_ * OH_);
    int w = r / OH_;
    int h = r - w * OH_;
    float* op = out + ((size_t)(b * F_) * OW_ + w) * OH_ + h;
#pragma unroll
    for (int mi = 0; mi < 4; ++mi) {
      int fbase = wr * 64 + mi * 16 + l4 * 4;
#pragma unroll
      for (int q = 0; q < 4; ++q) {
        op[(size_t)(fbase + q) * (OW_ * OH_)] = acc[mi][ni][q];
      }
    }
  }
}

// ---------------- correctness fallback (ws too small) ----------------
__global__ void naive_conv(const float* __restrict__ in, const float* __restrict__ ker,
                           float* __restrict__ out) {
  int idx = blockIdx.x * 256 + threadIdx.x;
  const int total = B_ * F_ * OW_ * OH_;
  if (idx >= total) return;
  int h = idx % OH_;
  int w = (idx / OH_) % OW_;
  int f = (idx / (OW_ * OH_)) % F_;
  int b = idx / (F_ * OW_ * OH_);
  float s = 0.f;
  for (int tap = 0; tap < 9; ++tap) {
    int i = tap / 3, j = tap % 3;
    const float* ip = in + ((size_t)b * C_ * H_ + (h + j)) * W_ + (w + i);
    const float* kp = ker + (size_t)f * KK_ + tap * C_;
    for (int c = 0; c < C_; ++c) s += ip[(size_t)c * HW_] * kp[c];
  }
  out[idx] = s;
}

extern "C" void kernel_launch(void* const* d_in, const int* in_sizes, int n_in,
                              void* d_out, int out_size, void* d_ws, size_t ws_size,
                              hipStream_t stream) {
  const float* in = (const float*)d_in[0];
  const float* ker = (const float*)d_in[1];
  float* out = (float*)d_out;

  const size_t xElems = (size_t)B_ * H_ * W_ * C_;  // 6,422,528
  const size_t kElems = (size_t)F_ * KK_;           // 73,728
  const size_t need = xElems * 2 * 2 + kElems * 2 * 2;

  if (ws_size < need) {
    int total = B_ * F_ * OW_ * OH_;
    naive_conv<<<(total + 255) / 256, 256, 0, stream>>>(in, ker, out);
    return;
  }

  u16* xH = (u16*)d_ws;
  u16* xL = xH + xElems;
  u16* kH = xL + xElems;
  u16* kL = kH + kElems;

  prep_input<<<B_ * H_, 256, 0, stream>>>(in, xH, xL);
  prep_ker<<<(int)((kElems + 255) / 256), 256, 0, stream>>>(ker, kH, kL);
  conv_mfma<<<(NPOS + 127) / 128, 256, 0, stream>>>(xH, xL, kH, kL, out);
}